// Round 8
// baseline (785.482 us; speedup 1.0000x reference)
//
#include <hip/hip_runtime.h>

typedef unsigned int UI;
typedef unsigned long long ULL;
typedef _Float16 f16;
typedef _Float16 h8 __attribute__((ext_vector_type(8)));
typedef float f32x4 __attribute__((ext_vector_type(4)));
typedef float fl2 __attribute__((ext_vector_type(2)));
typedef UI ui2 __attribute__((ext_vector_type(2)));

#define NB_PTS 4096
#define MB_SEL 1024
#define KNBR   64
#define NCLOUD 4
#define NCENT  4096

// ws layout (f16): Wt1[128][96] @0 ; Wt2[128][128] @12288 ; Wt3[256][128] @28672
#define WT2_OFF 12288
#define WT3_OFF 28672
#define WS_ELEMS 61440
#define WSFLAG_MAGIC 0x1234ABCDu   // != 0 (memset) and != 0xAAAAAAAA (poison)

// dynamic-LDS layout (bytes). conv view (all < 50 KB):
#define OFF_H1   13312   // h1s [64*136 f16]
#define OFF_H2   30720   // h2s [64*136 f16]
#define OFF_PMAX 48128   // pmax [256 f32]
#define OFF_MASK 49152   // masks [64 ULL]
#define OFF_NBR  49664   // nbrS [64 int]
#define OFF_NV   49920   // nvS int
#define OFF_SHS  49924   // spun sel int
// fps view: keys f64[2][8] @65536, coord slots float4[2][8] @65664
#define OFF_SLOT 65536
// 84 KB > 160/2 KB  =>  exactly ONE block per CU (fps CUs run interference-free)
#define DYN_LDS  86016

// exact np-order squared distance, f64 (radius predicate — proven)
__device__ __forceinline__ double d2_np64(double dx, double dy, double dz) {
  return __dadd_rn(__dadd_rn(__dmul_rn(dx, dx), __dmul_rn(dy, dy)),
                   __dmul_rn(dz, dz));
}

// --- key-as-f64 (r3/r7-proven) ----------------------------------------------
// key = (bits32(dist) << 32) | ~idx. dist in [0,3] fp32 (or +inf init bits
// 0x7f800000 as hi word -> f64 exponent field 0x7f8 != all-ones => finite).
// For non-negative finite f64, value ordering == u64 bit ordering:
//   v_min_f64(acc, cand) with identical lo words == np.minimum (bit-exact);
//   v_max_f64 across points: ties order by ~idx => smaller idx wins
//   == np.argmax first-max (bit-exact).
// Subnormal-range keys (dist~0) can never be the argmax; f64 denorms are not
// flushed; no NaNs possible. idx unique per point => keys globally unique
// (the owning-lane self-identification below relies on this).
// ----------------------------------------------------------------------------

// one f64-max DPP step (bound_ctrl=1 -> OOB lanes read 0 = +0.0, never wins)
template <int CTRL>
__device__ __forceinline__ double dpp_fmax_step(double cur) {
  ULL cu = __builtin_bit_cast(ULL, cur);
  UI lo = (UI)cu, hi = (UI)(cu >> 32);
  UI nl = (UI)__builtin_amdgcn_update_dpp(0, (int)lo, CTRL, 0xf, 0xf, true);
  UI nh = (UI)__builtin_amdgcn_update_dpp(0, (int)hi, CTRL, 0xf, 0xf, true);
  double nv = __builtin_bit_cast(double, ((ULL)nh << 32) | (ULL)nl);
  return fmax(cur, nv);    // v_max_f64
}

// ---------------------------------------------------------------------------
// ONE fused kernel, 512-thr blocks, 1 block/CU (84 KB dynamic LDS).
//
// blocks 0..3: FPS — r7 base (8 waves x 8 pts/lane, f64 keys in the scan,
//   DPP f64-max reduce, barrier sync). ROUND-8 CHANGE: the two DEPENDENT
//   LDS round trips per iteration (read key slots -> merge -> winner ->
//   read pp[winner]) become ONE static-address round trip:
//     pre-barrier: lane63 writes the wave-max key (as before); the OWNING
//       LANE of the wave's candidate (lane == j&63, since j mod 512 = tid;
//       point-within-lane = j>>9, a readlane-uniform index -> SCC-branch
//       switch, no cndmask tree) writes the candidate COORDS to cslot[wv].
//     post-barrier: all reads are static-address (8 key slots broadcast +
//       lane reads cslot[lane&7]) -> they pipeline into ~one LDS latency.
//       After the key merge, winner coords come via 3x v_readlane from
//       lane (winner>>6)&7 (~15 cyc) instead of a 150-200 cyc LDS read.
//   pp[] (64 KB staged cloud) is now DEAD -> deleted, along with the
//   staging barrier (LDS slots are only touched in-loop; every read
//   follows the in-loop barrier; double-buffer reuse argument unchanged).
//   Selection math bit-identical to r7.
// block 4: weight prep (f32 -> f16 transposed [n][k]) + release flag.
// blocks 5..4100: conv centroid c=idx-5 (r14-proven bitwise path, untouched).
// ---------------------------------------------------------------------------
__global__ __launch_bounds__(512, 2) void fused_kernel(
    const float* __restrict__ x, const float* __restrict__ pos,
    const float* __restrict__ W1, const float* __restrict__ b1,
    const float* __restrict__ W2, const float* __restrict__ b2,
    const float* __restrict__ W3, const float* __restrict__ b3,
    f16* __restrict__ ws, UI* __restrict__ wsflag,
    float* __restrict__ selstash, float* __restrict__ out_x,
    float* __restrict__ out_pos, float* __restrict__ out_batch) {
  extern __shared__ char smem[];
  const int tid  = threadIdx.x;
  const int lane = tid & 63;
  const int wv   = tid >> 6;

  // ======================= role: weight prep (block 4) =====================
  if (blockIdx.x == NCLOUD) {
    for (int t = tid; t < WS_ELEMS; t += 512) {
      if (t < WT2_OFF) {                       // Wt1[n][k] : 128 x 96
        int n = t / 96, k = t - n * 96;
        ws[t] = (k < 67) ? (f16)W1[k * 128 + n] : (f16)0.f;
      } else if (t < WT3_OFF) {                // Wt2[n][k] : 128 x 128
        int u = t - WT2_OFF;
        int n = u >> 7, k = u & 127;
        ws[t] = (f16)W2[k * 128 + n];
      } else {                                 // Wt3[n][k] : 256 x 128
        int u = t - WT3_OFF;
        int n = u >> 7, k = u & 127;
        ws[t] = (f16)W3[k * 256 + n];
      }
    }
    __syncthreads();   // drains all waves' stores before publishing
    if (tid == 0)
      __hip_atomic_store(wsflag, WSFLAG_MAGIC, __ATOMIC_RELEASE,
                         __HIP_MEMORY_SCOPE_AGENT);
    return;
  }

  // ============================ role: FPS (0..3) ===========================
  if (blockIdx.x < NCLOUD) {
#pragma clang fp contract(off)
    asm volatile("s_setprio 3");
    double* kslot = (double*)(smem + OFF_SLOT);          // [2][8] f64 keys
    float4* cslot = (float4*)(smem + OFF_SLOT + 128);    // [2][8] cand coords
    const int b = blockIdx.x;

    // 8 pts/lane register-resident (coords + f64 key accumulators). No LDS
    // staging: coords now travel through the per-iteration slots.
    fl2 mx[4], my[4], mz[4];
    double key[8];
    UI nlo[8];
#pragma unroll
    for (int t = 0; t < 4; ++t) {
      int j0 = tid + (2 * t) * 512;
      int j1 = tid + (2 * t + 1) * 512;
      size_t a0 = ((size_t)b * NB_PTS + j0) * 3;
      size_t a1 = ((size_t)b * NB_PTS + j1) * 3;
      float X0 = pos[a0], Y0 = pos[a0 + 1], Z0 = pos[a0 + 2];
      float X1 = pos[a1], Y1 = pos[a1 + 1], Z1 = pos[a1 + 2];
      mx[t] = fl2{X0, X1}; my[t] = fl2{Y0, Y1}; mz[t] = fl2{Z0, Z1};
      nlo[2 * t]     = ~(UI)j0;
      nlo[2 * t + 1] = ~(UI)j1;
      ui2 k0; k0.x = nlo[2 * t];     k0.y = 0x7f800000u;   // dist = +inf bits
      ui2 k1; k1.x = nlo[2 * t + 1]; k1.y = 0x7f800000u;
      key[2 * t]     = __builtin_bit_cast(double, k0);
      key[2 * t + 1] = __builtin_bit_cast(double, k1);
    }
    if (tid == 0)
      __hip_atomic_store(&selstash[b * MB_SEL], 1.0f, __ATOMIC_RELAXED,
                         __HIP_MEMORY_SCOPE_AGENT);   // sel 0, encoded +1
    // NO staging barrier: LDS slots are written only inside the loop and
    // every slot read follows the in-loop barrier (skew-safe).

    // k=1 query point = point 0 of this cloud, straight from global.
    const size_t qb0 = (size_t)b * NB_PTS * 3;
    float wx = pos[qb0], wy = pos[qb0 + 1], wz = pos[qb0 + 2];

    for (int k = 1; k < MB_SEL; ++k) {
#pragma unroll
      for (int t = 0; t < 4; ++t) {
        fl2 dx = mx[t] - wx;            // v_pk ops; per-comp RN == scalar np
        fl2 dy = my[t] - wy;
        fl2 dz = mz[t] - wz;
        fl2 dd = (dx * dx + dy * dy) + dz * dz;   // np order, contract off
        ui2 c0; c0.x = nlo[2 * t];     c0.y = __float_as_uint(dd.x);
        ui2 c1; c1.x = nlo[2 * t + 1]; c1.y = __float_as_uint(dd.y);
        key[2 * t]     = fmin(key[2 * t],
                              __builtin_bit_cast(double, c0));  // v_min_f64
        key[2 * t + 1] = fmin(key[2 * t + 1],
                              __builtin_bit_cast(double, c1));
      }
      // per-lane argmax: depth-3 v_max_f64 tree over the 8 key accumulators
      double a0 = fmax(key[0], key[1]), a1 = fmax(key[2], key[3]);
      double a2 = fmax(key[4], key[5]), a3 = fmax(key[6], key[7]);
      double wk = fmax(fmax(a0, a1), fmax(a2, a3));
      // wave argmax: 6-step DPP f64-max chain -> lane 63 holds wave max
      wk = dpp_fmax_step<0x111>(wk);    // row_shr:1
      wk = dpp_fmax_step<0x112>(wk);    // row_shr:2
      wk = dpp_fmax_step<0x114>(wk);    // row_shr:4
      wk = dpp_fmax_step<0x118>(wk);    // row_shr:8
      wk = dpp_fmax_step<0x142>(wk);    // row_bcast:15
      wk = dpp_fmax_step<0x143>(wk);    // row_bcast:31
      const int buf = (k & 1) * 8;
      if (lane == 63) kslot[buf + wv] = wk;
      // coords publication: broadcast this wave's candidate idx from lane 63;
      // the OWNING lane (j mod 512 = tid => lane == j&63, and the wave is
      // necessarily this one) writes the candidate coords. Point-within-lane
      // s8 = j>>9 is wave-uniform => SCC-branch switch, no cndmask tree.
      UI jwlo = (UI)__builtin_amdgcn_readlane(
          (int)(UI)__builtin_bit_cast(ULL, wk), 63);
      const int jw = (int)(~jwlo) & (NB_PTS - 1);
      if (lane == (jw & 63)) {
        const int s8 = jw >> 9;
        float cx, cy, cz;
        switch (s8) {
          case 0:  cx = mx[0].x; cy = my[0].x; cz = mz[0].x; break;
          case 1:  cx = mx[0].y; cy = my[0].y; cz = mz[0].y; break;
          case 2:  cx = mx[1].x; cy = my[1].x; cz = mz[1].x; break;
          case 3:  cx = mx[1].y; cy = my[1].y; cz = mz[1].y; break;
          case 4:  cx = mx[2].x; cy = my[2].x; cz = mz[2].x; break;
          case 5:  cx = mx[2].y; cy = my[2].y; cz = mz[2].y; break;
          case 6:  cx = mx[3].x; cy = my[3].x; cz = mz[3].x; break;
          default: cx = mx[3].y; cy = my[3].y; cz = mz[3].y; break;
        }
        cslot[buf + wv] = make_float4(cx, cy, cz, 0.f);
      }
      // raw barrier: drain only LDS (both slot writes visible), never vmcnt —
      // the selstash global store stays fire-and-forget (r2-proven).
      asm volatile("s_waitcnt lgkmcnt(0)\n\ts_barrier" ::: "memory");
      // post-barrier: ALL addresses static -> reads pipeline into one LDS
      // round trip. Lane i holds cslot coords of wave (i&7).
      const double* sp = kslot + buf;
      double s0 = sp[0], s1 = sp[1], s2 = sp[2], s3 = sp[3];
      double s4 = sp[4], s5 = sp[5], s6 = sp[6], s7 = sp[7];
      float4 cw = cslot[buf + (lane & 7)];
      double m01 = fmax(s0, s1);        // tree merge, v_max_f64 each
      double m23 = fmax(s2, s3);
      double m45 = fmax(s4, s5);
      double m67 = fmax(s6, s7);
      double mk  = fmax(fmax(m01, m23), fmax(m45, m67));
      int winner = (int)(~(UI)__builtin_bit_cast(ULL, mk));
      if (tid == 0)
        __hip_atomic_store(&selstash[b * MB_SEL + k], (float)(winner + 1),
                           __ATOMIC_RELAXED, __HIP_MEMORY_SCOPE_AGENT);
      // winner coords: readlane from the winning wave's coord-holder lane
      const int wvstar = (winner >> 6) & 7;
      wx = __builtin_bit_cast(float, __builtin_amdgcn_readlane(
               __builtin_bit_cast(int, cw.x), wvstar));
      wy = __builtin_bit_cast(float, __builtin_amdgcn_readlane(
               __builtin_bit_cast(int, cw.y), wvstar));
      wz = __builtin_bit_cast(float, __builtin_amdgcn_readlane(
               __builtin_bit_cast(int, cw.z), wvstar));
    }
    return;
  }

  // ============================ role: conv =================================
  f16* featA  = (f16*)smem;
  f16* h1s    = (f16*)(smem + OFF_H1);
  f16* h2s    = (f16*)(smem + OFF_H2);
  float* pmax = (float*)(smem + OFF_PMAX);
  ULL* masks  = (ULL*)(smem + OFF_MASK);
  int* nbrS   = (int*)(smem + OFF_NBR);
  int* nvP    = (int*)(smem + OFF_NV);
  int* shS    = (int*)(smem + OFF_SHS);

  const int c  = (int)blockIdx.x - (NCLOUD + 1);
  const int k  = c >> 2;
  const int b  = c & 3;
  const int cg = b * MB_SEL + k;     // global centroid id (output index)

  // gate 1: weights ready (release/acquire covers the non-atomic ws payload)
  if (tid == 0) {
    while (__hip_atomic_load(wsflag, __ATOMIC_ACQUIRE,
                             __HIP_MEMORY_SCOPE_AGENT) != WSFLAG_MAGIC)
      __builtin_amdgcn_s_sleep(2);
  }
  __syncthreads();

  // B1/B2 + bias preload (8 waves own 16 cols each for L1/L2, 32 for L3)
  const int n    = lane & 15;
  const int quad = lane >> 4;
  const int col  = wv * 16 + n;       // L1/L2 column
  h8 B1f[3], B2f[4];
  float bv1, bv2, bv3[2];
  bv1 = b1[col];
  bv2 = b2[col];
#pragma unroll
  for (int kt = 0; kt < 3; ++kt)
    B1f[kt] = *(const h8*)(ws + col * 96 + kt * 32 + quad * 8);
#pragma unroll
  for (int kt = 0; kt < 4; ++kt)
    B2f[kt] = *(const h8*)(ws + WT2_OFF + col * 128 + kt * 32 + quad * 8);
#pragma unroll
  for (int ct = 0; ct < 2; ++ct) bv3[ct] = b3[(2 * wv + ct) * 16 + n];

  // gate 2: own sel ready (value IS the payload; winner+1 >= 1;
  // both init states — memset-0 and 0xAA poison — read as "not ready")
  if (tid == 0) {
    float v;
    for (;;) {
      v = __hip_atomic_load(&selstash[cg], __ATOMIC_RELAXED,
                            __HIP_MEMORY_SCOPE_AGENT);
      if (v >= 1.0f) break;
      __builtin_amdgcn_s_sleep(8);
    }
    *shS = (int)v - 1;
  }
  __syncthreads();
  const int s = (*shS) & (NB_PTS - 1);

  const size_t qb = ((size_t)(b * NB_PTS + s)) * 3;
  const float qxf = pos[qb], qyf = pos[qb + 1], qzf = pos[qb + 2];
  const double qx = (double)qxf, qy = (double)qyf, qz = (double)qzf;
  const double RR = 0.2 * 0.2;

  // radius: in-ball bitmask over all 4096 points (f64, np-exact).
  // 8 waves x 8 chunks = 64 chunks of 64 points.
#pragma unroll
  for (int it = 0; it < 8; ++it) {
    const int ch = wv * 8 + it;
    const int j  = ch * 64 + lane;
    const size_t pb = ((size_t)b * NB_PTS + j) * 3;
    double d2 = d2_np64((double)pos[pb] - qx, (double)pos[pb + 1] - qy,
                        (double)pos[pb + 2] - qz);
    ULL m = __ballot(d2 <= RR);
    if (lane == 0) masks[ch] = m;
  }
  __syncthreads();

  // wave 0: first-64 in-ball extraction (ascending index)
  if (tid < 64) {
    ULL m = masks[tid];
    int pc = __popcll(m);
    int incl = pc;
#pragma unroll
    for (int off = 1; off < 64; off <<= 1) {
      int o = __shfl_up(incl, off, 64);
      if (tid >= off) incl += o;
    }
    int base = incl - pc;
    int tot  = __shfl(incl, 63, 64);
    int nvw  = min(tot, KNBR);
    if (tid == 63) *nvP = nvw;
    int slot = base;
    ULL mm = m;
    while (mm && slot < KNBR) {
      int bit = __ffsll(mm) - 1;
      nbrS[slot++] = tid * 64 + bit;
      mm &= mm - 1;
    }
    if (tid >= nvw) nbrS[tid] = s;
  }
  __syncthreads();
  const int nv = *nvP;

  // gather: feat=[x_j, pos_j-pos_i, 0-pad] as f16, rows 0..63 (8 thr/row)
  {
    const int r = tid >> 3;
    const int part = tid & 7;
    const int g = nbrS[r];
    const float* xrow = x + (((size_t)(b * NB_PTS + g)) << 6) + part * 8;
    float4 u0 = *(const float4*)(xrow);
    float4 u1 = *(const float4*)(xrow + 4);
    h8 o0;
    o0[0]=(f16)u0.x; o0[1]=(f16)u0.y; o0[2]=(f16)u0.z; o0[3]=(f16)u0.w;
    o0[4]=(f16)u1.x; o0[5]=(f16)u1.y; o0[6]=(f16)u1.z; o0[7]=(f16)u1.w;
    *(h8*)(featA + r * 104 + part * 8) = o0;
    if (part == 7) {
      size_t gb = ((size_t)(b * NB_PTS + g)) * 3;
      h8 rv = {(f16)0.f,(f16)0.f,(f16)0.f,(f16)0.f,(f16)0.f,(f16)0.f,(f16)0.f,(f16)0.f};
      rv[0] = (f16)(pos[gb]     - qxf);
      rv[1] = (f16)(pos[gb + 1] - qyf);
      rv[2] = (f16)(pos[gb + 2] - qzf);
      h8 z = {(f16)0.f,(f16)0.f,(f16)0.f,(f16)0.f,(f16)0.f,(f16)0.f,(f16)0.f,(f16)0.f};
      *(h8*)(featA + r * 104 + 64) = rv;
      *(h8*)(featA + r * 104 + 72) = z;
      *(h8*)(featA + r * 104 + 80) = z;
      *(h8*)(featA + r * 104 + 88) = z;
    }
  }
  __syncthreads();

  // L1: 67(->96) -> 128 ; wave w owns cols [16w,16w+16)
#pragma unroll
  for (int at = 0; at < 4; ++at) {
    f32x4 acc = {0.f, 0.f, 0.f, 0.f};
#pragma unroll
    for (int kt = 0; kt < 3; ++kt) {
      h8 a = *(const h8*)(featA + (at * 16 + n) * 104 + kt * 32 + quad * 8);
      acc = __builtin_amdgcn_mfma_f32_16x16x32_f16(a, B1f[kt], acc, 0, 0, 0);
    }
#pragma unroll
    for (int r = 0; r < 4; ++r)
      h1s[(at * 16 + quad * 4 + r) * 136 + col] = (f16)fmaxf(acc[r] + bv1, 0.f);
  }
  __syncthreads();

  // L2: 128 -> 128
#pragma unroll
  for (int at = 0; at < 4; ++at) {
    f32x4 acc = {0.f, 0.f, 0.f, 0.f};
#pragma unroll
    for (int kt = 0; kt < 4; ++kt) {
      h8 a = *(const h8*)(h1s + (at * 16 + n) * 136 + kt * 32 + quad * 8);
      acc = __builtin_amdgcn_mfma_f32_16x16x32_f16(a, B2f[kt], acc, 0, 0, 0);
    }
#pragma unroll
    for (int r = 0; r < 4; ++r)
      h2s[(at * 16 + quad * 4 + r) * 136 + col] = (f16)fmaxf(acc[r] + bv2, 0.f);
  }
  __syncthreads();

  // L3: 128 -> 256, wave w owns cols [32w,32w+32); B3 streamed from L2
  float vm[2] = {0.f, 0.f};   // valid max >= 0 (relu, nv>=1)
#pragma unroll
  for (int at = 0; at < 4; ++at) {
#pragma unroll
    for (int ct = 0; ct < 2; ++ct) {
      const int c3 = (2 * wv + ct) * 16 + n;
      f32x4 acc = {0.f, 0.f, 0.f, 0.f};
#pragma unroll
      for (int kt = 0; kt < 4; ++kt) {
        h8 a = *(const h8*)(h2s + (at * 16 + n) * 136 + kt * 32 + quad * 8);
        h8 wfr = *(const h8*)(ws + WT3_OFF + c3 * 128 + kt * 32 + quad * 8);
        acc = __builtin_amdgcn_mfma_f32_16x16x32_f16(a, wfr, acc, 0, 0, 0);
      }
#pragma unroll
      for (int r = 0; r < 4; ++r) {
        float h = fmaxf(acc[r] + bv3[ct], 0.f);
        const int row = at * 16 + quad * 4 + r;
        vm[ct] = fmaxf(vm[ct], row < nv ? h : 0.f);
      }
    }
  }
#pragma unroll
  for (int ct = 0; ct < 2; ++ct) {
    vm[ct] = fmaxf(vm[ct], __shfl_xor(vm[ct], 16, 64));
    vm[ct] = fmaxf(vm[ct], __shfl_xor(vm[ct], 32, 64));
  }
  if (quad == 0) {
#pragma unroll
    for (int ct = 0; ct < 2; ++ct) pmax[(2 * wv + ct) * 16 + n] = vm[ct];
  }
  __syncthreads();

  if (tid < 256) out_x[(size_t)cg * 256 + tid] = pmax[tid];
  if (tid < 3) out_pos[cg * 3 + tid] = pos[qb + tid];
  if (tid == 0) out_batch[cg] = (float)b;   // overwrite sel stash
}

extern "C" void kernel_launch(void* const* d_in, const int* in_sizes, int n_in,
                              void* d_out, int out_size, void* d_ws, size_t ws_size,
                              hipStream_t stream) {
  const float* x   = (const float*)d_in[0];
  const float* pos = (const float*)d_in[1];
  // d_in[2] = batch (int32), unused (layout known)
  const float* W1 = (const float*)d_in[3];
  const float* b1 = (const float*)d_in[4];
  const float* W2 = (const float*)d_in[5];
  const float* b2 = (const float*)d_in[6];
  const float* W3 = (const float*)d_in[7];
  const float* b3 = (const float*)d_in[8];

  float* out = (float*)d_out;
  float* out_pos   = out + (size_t)NCENT * 256;
  float* out_batch = out_pos + (size_t)NCENT * 3;   // doubles as sel channel
  f16* ws    = (f16*)d_ws;                          // 122880 B f16 weights
  UI* wsflag = (UI*)((char*)d_ws + 2 * WS_ELEMS);   // publish flag

  // opt-in to >64 KB dynamic LDS (idempotent; host-side, capture-safe)
  hipFuncSetAttribute((const void*)fused_kernel,
                      hipFuncAttributeMaxDynamicSharedMemorySize, DYN_LDS);

  fused_kernel<<<NCLOUD + 1 + NCENT, 512, DYN_LDS, stream>>>(
      x, pos, W1, b1, W2, b2, W3, b3, ws, wsflag,
      out_batch, out, out_pos, out_batch);
}

// Round 9
// 640.647 us; speedup vs baseline: 1.2261x; 1.2261x over previous
//
#include <hip/hip_runtime.h>

typedef unsigned int UI;
typedef unsigned long long ULL;
typedef _Float16 f16;
typedef _Float16 h8 __attribute__((ext_vector_type(8)));
typedef float f32x4 __attribute__((ext_vector_type(4)));
typedef float fl2 __attribute__((ext_vector_type(2)));
typedef UI ui2 __attribute__((ext_vector_type(2)));

#define NB_PTS 4096
#define MB_SEL 1024
#define KNBR   64
#define NCLOUD 4
#define NCENT  4096

// ws layout (f16): Wt1[128][96] @0 ; Wt2[128][128] @12288 ; Wt3[256][128] @28672
#define WT2_OFF 12288
#define WT3_OFF 28672
#define WS_ELEMS 61440
#define WSFLAG_MAGIC 0x1234ABCDu   // != 0 (memset) and != 0xAAAAAAAA (poison)

// dynamic-LDS layout (bytes). conv view (all < 50 KB):
#define OFF_H1   13312   // h1s [64*136 f16]
#define OFF_H2   30720   // h2s [64*136 f16]
#define OFF_PMAX 48128   // pmax [256 f32]
#define OFF_MASK 49152   // masks [64 ULL]
#define OFF_NBR  49664   // nbrS [64 int]
#define OFF_NV   49920   // nvS int
#define OFF_SHS  49924   // spun sel int
// fps view: pp float4[4096] @0 (64 KB), key slots f64[2][8] @65536
#define OFF_SLOT 65536
// 84 KB > 160/2 KB  =>  exactly ONE block per CU (fps CUs run interference-free)
#define DYN_LDS  86016

// exact np-order squared distance, f64 (radius predicate — proven)
__device__ __forceinline__ double d2_np64(double dx, double dy, double dz) {
  return __dadd_rn(__dadd_rn(__dmul_rn(dx, dx), __dmul_rn(dy, dy)),
                   __dmul_rn(dz, dz));
}

// --- key-as-f64 (r3/r7-proven) ----------------------------------------------
// key = (bits32(dist) << 32) | ~idx. dist in [0,3] fp32 (or the +inf init
// 0x7f800000 as hi word -> f64 exponent field 0x7f8 != all-ones => finite).
// For non-negative finite f64, value ordering == u64 bit ordering, so:
//   v_min_f64(key_acc, cand) with IDENTICAL lo words (same point's ~idx)
//     == np.minimum on the f32 dist, bit-exact.
//   v_max_f64 across points: equal dist => larger ~idx = smaller idx wins
//     == np.argmax first-max, bit-exact.
// Subnormal-range keys (dist~0) can never be the argmax and CDNA f64 min/max
// do not flush denormals. No NaNs possible (finite squares/sums).
// ----------------------------------------------------------------------------

// one f64-max DPP step (bound_ctrl=1 -> OOB lanes read 0 = +0.0, never wins)
template <int CTRL>
__device__ __forceinline__ double dpp_fmax_step(double cur) {
  ULL cu = __builtin_bit_cast(ULL, cur);
  UI lo = (UI)cu, hi = (UI)(cu >> 32);
  UI nl = (UI)__builtin_amdgcn_update_dpp(0, (int)lo, CTRL, 0xf, 0xf, true);
  UI nh = (UI)__builtin_amdgcn_update_dpp(0, (int)hi, CTRL, 0xf, 0xf, true);
  double nv = __builtin_bit_cast(double, ((ULL)nh << 32) | (ULL)nl);
  return fmax(cur, nv);    // v_max_f64
}

// ---------------------------------------------------------------------------
// ONE fused kernel, 512-thr blocks, 1 block/CU (84 KB dynamic LDS).
//
// blocks 0..3: FPS — r7 kernel (measured best: 589 us dispatch / 641 us dur),
//   REVERTED from r8 (+24% regression: DPP->readlane hazard + exec-branch
//   switch + extra ds_write on the pre-barrier drain path + VGPR-indexed
//   readlanes post-merge cost ~+330 cyc/iter against the -130 cyc pp-read
//   they replaced. Lesson: pre-barrier path must stay branch/readlane-free).
//   Structure: 8 waves x 8 pts/lane register-resident; f64 keys in the scan
//   (one v_min_f64 per point-pair-half); depth-3 v_max_f64 per-lane tree;
//   6-step DPP f64-max chain; lane63 slot write; raw lgkmcnt-only barrier;
//   8-slot f64 merge; one pp[winner] LDS broadcast read (load issued before
//   the fire-and-forget selstash store — the only r9 delta vs r7).
//   Design space exhausted: sync topologies (barrier > ring poll > vmcnt),
//   wave layouts (4-wave VGPR-dead x3), scan arithmetic (f64 keys, proven),
//   LDS-trip fusion (r8, net-negative). ~576 ns/iter is this structure's
//   floor: ~450 cyc issue + 2 LDS round trips + DPP serial + barrier.
// block 4: weight prep (f32 -> f16 transposed [n][k]) + release flag.
// blocks 5..4100: conv centroid c=idx-5 (r14-proven bitwise path, untouched).
// ---------------------------------------------------------------------------
__global__ __launch_bounds__(512, 2) void fused_kernel(
    const float* __restrict__ x, const float* __restrict__ pos,
    const float* __restrict__ W1, const float* __restrict__ b1,
    const float* __restrict__ W2, const float* __restrict__ b2,
    const float* __restrict__ W3, const float* __restrict__ b3,
    f16* __restrict__ ws, UI* __restrict__ wsflag,
    float* __restrict__ selstash, float* __restrict__ out_x,
    float* __restrict__ out_pos, float* __restrict__ out_batch) {
  extern __shared__ char smem[];
  const int tid  = threadIdx.x;
  const int lane = tid & 63;
  const int wv   = tid >> 6;

  // ======================= role: weight prep (block 4) =====================
  if (blockIdx.x == NCLOUD) {
    for (int t = tid; t < WS_ELEMS; t += 512) {
      if (t < WT2_OFF) {                       // Wt1[n][k] : 128 x 96
        int n = t / 96, k = t - n * 96;
        ws[t] = (k < 67) ? (f16)W1[k * 128 + n] : (f16)0.f;
      } else if (t < WT3_OFF) {                // Wt2[n][k] : 128 x 128
        int u = t - WT2_OFF;
        int n = u >> 7, k = u & 127;
        ws[t] = (f16)W2[k * 128 + n];
      } else {                                 // Wt3[n][k] : 256 x 128
        int u = t - WT3_OFF;
        int n = u >> 7, k = u & 127;
        ws[t] = (f16)W3[k * 256 + n];
      }
    }
    __syncthreads();   // drains all waves' stores before publishing
    if (tid == 0)
      __hip_atomic_store(wsflag, WSFLAG_MAGIC, __ATOMIC_RELEASE,
                         __HIP_MEMORY_SCOPE_AGENT);
    return;
  }

  // ============================ role: FPS (0..3) ===========================
  if (blockIdx.x < NCLOUD) {
#pragma clang fp contract(off)
    asm volatile("s_setprio 3");
    float4* pp    = (float4*)smem;             // 64 KB
    double* kslot = (double*)(smem + OFF_SLOT);// [2][8] f64 keys
    const int b = blockIdx.x;

    fl2 mx[4], my[4], mz[4];
    double key[8];        // per-point f64 key accumulators {~idx, distbits}
    UI nlo[8];            // per-point ~idx (loop-invariant)
#pragma unroll
    for (int t = 0; t < 4; ++t) {
      int j0 = tid + (2 * t) * 512;
      int j1 = tid + (2 * t + 1) * 512;
      size_t a0 = ((size_t)b * NB_PTS + j0) * 3;
      size_t a1 = ((size_t)b * NB_PTS + j1) * 3;
      float X0 = pos[a0], Y0 = pos[a0 + 1], Z0 = pos[a0 + 2];
      float X1 = pos[a1], Y1 = pos[a1 + 1], Z1 = pos[a1 + 2];
      pp[j0] = make_float4(X0, Y0, Z0, 0.f);
      pp[j1] = make_float4(X1, Y1, Z1, 0.f);
      mx[t] = fl2{X0, X1}; my[t] = fl2{Y0, Y1}; mz[t] = fl2{Z0, Z1};
      nlo[2 * t]     = ~(UI)j0;
      nlo[2 * t + 1] = ~(UI)j1;
      ui2 k0; k0.x = nlo[2 * t];     k0.y = 0x7f800000u;   // dist = +inf bits
      ui2 k1; k1.x = nlo[2 * t + 1]; k1.y = 0x7f800000u;
      key[2 * t]     = __builtin_bit_cast(double, k0);
      key[2 * t + 1] = __builtin_bit_cast(double, k1);
    }
    if (tid == 0)
      __hip_atomic_store(&selstash[b * MB_SEL], 1.0f, __ATOMIC_RELAXED,
                         __HIP_MEMORY_SCOPE_AGENT);   // sel 0, encoded +1
    __syncthreads();   // staging fence (once)

    int cur = 0;
    for (int k = 1; k < MB_SEL; ++k) {
      float4 w = pp[cur];               // one b128 broadcast read
#pragma unroll
      for (int t = 0; t < 4; ++t) {
        fl2 dx = mx[t] - w.x;           // v_pk ops; per-comp RN == scalar np
        fl2 dy = my[t] - w.y;
        fl2 dz = mz[t] - w.z;
        fl2 dd = (dx * dx + dy * dy) + dz * dz;   // np order, contract off
        ui2 c0; c0.x = nlo[2 * t];     c0.y = __float_as_uint(dd.x);
        ui2 c1; c1.x = nlo[2 * t + 1]; c1.y = __float_as_uint(dd.y);
        key[2 * t]     = fmin(key[2 * t],
                              __builtin_bit_cast(double, c0));  // v_min_f64
        key[2 * t + 1] = fmin(key[2 * t + 1],
                              __builtin_bit_cast(double, c1));
      }
      // per-lane argmax: depth-3 v_max_f64 tree over the 8 key accumulators
      double a0 = fmax(key[0], key[1]), a1 = fmax(key[2], key[3]);
      double a2 = fmax(key[4], key[5]), a3 = fmax(key[6], key[7]);
      double wk = fmax(fmax(a0, a1), fmax(a2, a3));
      // wave argmax: 6-step DPP f64-max chain -> lane 63 holds wave max
      wk = dpp_fmax_step<0x111>(wk);    // row_shr:1
      wk = dpp_fmax_step<0x112>(wk);    // row_shr:2
      wk = dpp_fmax_step<0x114>(wk);    // row_shr:4
      wk = dpp_fmax_step<0x118>(wk);    // row_shr:8
      wk = dpp_fmax_step<0x142>(wk);    // row_bcast:15
      wk = dpp_fmax_step<0x143>(wk);    // row_bcast:31
      const int buf = (k & 1) * 8;
      if (lane == 63) kslot[buf + wv] = wk;
      // raw barrier: drain only LDS (slot write visible), never vmcnt —
      // the selstash global store stays fire-and-forget (r2-proven).
      asm volatile("s_waitcnt lgkmcnt(0)\n\ts_barrier" ::: "memory");
      const double* sp = kslot + buf;
      double s0 = sp[0], s1 = sp[1], s2 = sp[2], s3 = sp[3];
      double s4 = sp[4], s5 = sp[5], s6 = sp[6], s7 = sp[7];
      double m01 = fmax(s0, s1);        // tree merge, v_max_f64 each
      double m23 = fmax(s2, s3);
      double m45 = fmax(s4, s5);
      double m67 = fmax(s6, s7);
      double mk  = fmax(fmax(m01, m23), fmax(m45, m67));
      int winner = (int)(~(UI)__builtin_bit_cast(ULL, mk));
      cur = winner;
      // next-iteration broadcast read issued BEFORE the fire-and-forget
      // store (scheduler gets the load as early as possible; r9 reorder).
      if (tid == 0)
        __hip_atomic_store(&selstash[b * MB_SEL + k], (float)(winner + 1),
                           __ATOMIC_RELAXED, __HIP_MEMORY_SCOPE_AGENT);
    }
    return;
  }

  // ============================ role: conv =================================
  f16* featA  = (f16*)smem;
  f16* h1s    = (f16*)(smem + OFF_H1);
  f16* h2s    = (f16*)(smem + OFF_H2);
  float* pmax = (float*)(smem + OFF_PMAX);
  ULL* masks  = (ULL*)(smem + OFF_MASK);
  int* nbrS   = (int*)(smem + OFF_NBR);
  int* nvP    = (int*)(smem + OFF_NV);
  int* shS    = (int*)(smem + OFF_SHS);

  const int c  = (int)blockIdx.x - (NCLOUD + 1);
  const int k  = c >> 2;
  const int b  = c & 3;
  const int cg = b * MB_SEL + k;     // global centroid id (output index)

  // gate 1: weights ready (release/acquire covers the non-atomic ws payload)
  if (tid == 0) {
    while (__hip_atomic_load(wsflag, __ATOMIC_ACQUIRE,
                             __HIP_MEMORY_SCOPE_AGENT) != WSFLAG_MAGIC)
      __builtin_amdgcn_s_sleep(2);
  }
  __syncthreads();

  // B1/B2 + bias preload (8 waves own 16 cols each for L1/L2, 32 for L3)
  const int n    = lane & 15;
  const int quad = lane >> 4;
  const int col  = wv * 16 + n;       // L1/L2 column
  h8 B1f[3], B2f[4];
  float bv1, bv2, bv3[2];
  bv1 = b1[col];
  bv2 = b2[col];
#pragma unroll
  for (int kt = 0; kt < 3; ++kt)
    B1f[kt] = *(const h8*)(ws + col * 96 + kt * 32 + quad * 8);
#pragma unroll
  for (int kt = 0; kt < 4; ++kt)
    B2f[kt] = *(const h8*)(ws + WT2_OFF + col * 128 + kt * 32 + quad * 8);
#pragma unroll
  for (int ct = 0; ct < 2; ++ct) bv3[ct] = b3[(2 * wv + ct) * 16 + n];

  // gate 2: own sel ready (value IS the payload; winner+1 >= 1;
  // both init states — memset-0 and 0xAA poison — read as "not ready")
  if (tid == 0) {
    float v;
    for (;;) {
      v = __hip_atomic_load(&selstash[cg], __ATOMIC_RELAXED,
                            __HIP_MEMORY_SCOPE_AGENT);
      if (v >= 1.0f) break;
      __builtin_amdgcn_s_sleep(8);
    }
    *shS = (int)v - 1;
  }
  __syncthreads();
  const int s = (*shS) & (NB_PTS - 1);

  const size_t qb = ((size_t)(b * NB_PTS + s)) * 3;
  const float qxf = pos[qb], qyf = pos[qb + 1], qzf = pos[qb + 2];
  const double qx = (double)qxf, qy = (double)qyf, qz = (double)qzf;
  const double RR = 0.2 * 0.2;

  // radius: in-ball bitmask over all 4096 points (f64, np-exact).
  // 8 waves x 8 chunks = 64 chunks of 64 points.
#pragma unroll
  for (int it = 0; it < 8; ++it) {
    const int ch = wv * 8 + it;
    const int j  = ch * 64 + lane;
    const size_t pb = ((size_t)b * NB_PTS + j) * 3;
    double d2 = d2_np64((double)pos[pb] - qx, (double)pos[pb + 1] - qy,
                        (double)pos[pb + 2] - qz);
    ULL m = __ballot(d2 <= RR);
    if (lane == 0) masks[ch] = m;
  }
  __syncthreads();

  // wave 0: first-64 in-ball extraction (ascending index)
  if (tid < 64) {
    ULL m = masks[tid];
    int pc = __popcll(m);
    int incl = pc;
#pragma unroll
    for (int off = 1; off < 64; off <<= 1) {
      int o = __shfl_up(incl, off, 64);
      if (tid >= off) incl += o;
    }
    int base = incl - pc;
    int tot  = __shfl(incl, 63, 64);
    int nvw  = min(tot, KNBR);
    if (tid == 63) *nvP = nvw;
    int slot = base;
    ULL mm = m;
    while (mm && slot < KNBR) {
      int bit = __ffsll(mm) - 1;
      nbrS[slot++] = tid * 64 + bit;
      mm &= mm - 1;
    }
    if (tid >= nvw) nbrS[tid] = s;
  }
  __syncthreads();
  const int nv = *nvP;

  // gather: feat=[x_j, pos_j-pos_i, 0-pad] as f16, rows 0..63 (8 thr/row)
  {
    const int r = tid >> 3;
    const int part = tid & 7;
    const int g = nbrS[r];
    const float* xrow = x + (((size_t)(b * NB_PTS + g)) << 6) + part * 8;
    float4 u0 = *(const float4*)(xrow);
    float4 u1 = *(const float4*)(xrow + 4);
    h8 o0;
    o0[0]=(f16)u0.x; o0[1]=(f16)u0.y; o0[2]=(f16)u0.z; o0[3]=(f16)u0.w;
    o0[4]=(f16)u1.x; o0[5]=(f16)u1.y; o0[6]=(f16)u1.z; o0[7]=(f16)u1.w;
    *(h8*)(featA + r * 104 + part * 8) = o0;
    if (part == 7) {
      size_t gb = ((size_t)(b * NB_PTS + g)) * 3;
      h8 rv = {(f16)0.f,(f16)0.f,(f16)0.f,(f16)0.f,(f16)0.f,(f16)0.f,(f16)0.f,(f16)0.f};
      rv[0] = (f16)(pos[gb]     - qxf);
      rv[1] = (f16)(pos[gb + 1] - qyf);
      rv[2] = (f16)(pos[gb + 2] - qzf);
      h8 z = {(f16)0.f,(f16)0.f,(f16)0.f,(f16)0.f,(f16)0.f,(f16)0.f,(f16)0.f,(f16)0.f};
      *(h8*)(featA + r * 104 + 64) = rv;
      *(h8*)(featA + r * 104 + 72) = z;
      *(h8*)(featA + r * 104 + 80) = z;
      *(h8*)(featA + r * 104 + 88) = z;
    }
  }
  __syncthreads();

  // L1: 67(->96) -> 128 ; wave w owns cols [16w,16w+16)
#pragma unroll
  for (int at = 0; at < 4; ++at) {
    f32x4 acc = {0.f, 0.f, 0.f, 0.f};
#pragma unroll
    for (int kt = 0; kt < 3; ++kt) {
      h8 a = *(const h8*)(featA + (at * 16 + n) * 104 + kt * 32 + quad * 8);
      acc = __builtin_amdgcn_mfma_f32_16x16x32_f16(a, B1f[kt], acc, 0, 0, 0);
    }
#pragma unroll
    for (int r = 0; r < 4; ++r)
      h1s[(at * 16 + quad * 4 + r) * 136 + col] = (f16)fmaxf(acc[r] + bv1, 0.f);
  }
  __syncthreads();

  // L2: 128 -> 128
#pragma unroll
  for (int at = 0; at < 4; ++at) {
    f32x4 acc = {0.f, 0.f, 0.f, 0.f};
#pragma unroll
    for (int kt = 0; kt < 4; ++kt) {
      h8 a = *(const h8*)(h1s + (at * 16 + n) * 136 + kt * 32 + quad * 8);
      acc = __builtin_amdgcn_mfma_f32_16x16x32_f16(a, B2f[kt], acc, 0, 0, 0);
    }
#pragma unroll
    for (int r = 0; r < 4; ++r)
      h2s[(at * 16 + quad * 4 + r) * 136 + col] = (f16)fmaxf(acc[r] + bv2, 0.f);
  }
  __syncthreads();

  // L3: 128 -> 256, wave w owns cols [32w,32w+32); B3 streamed from L2
  float vm[2] = {0.f, 0.f};   // valid max >= 0 (relu, nv>=1)
#pragma unroll
  for (int at = 0; at < 4; ++at) {
#pragma unroll
    for (int ct = 0; ct < 2; ++ct) {
      const int c3 = (2 * wv + ct) * 16 + n;
      f32x4 acc = {0.f, 0.f, 0.f, 0.f};
#pragma unroll
      for (int kt = 0; kt < 4; ++kt) {
        h8 a = *(const h8*)(h2s + (at * 16 + n) * 136 + kt * 32 + quad * 8);
        h8 wfr = *(const h8*)(ws + WT3_OFF + c3 * 128 + kt * 32 + quad * 8);
        acc = __builtin_amdgcn_mfma_f32_16x16x32_f16(a, wfr, acc, 0, 0, 0);
      }
#pragma unroll
      for (int r = 0; r < 4; ++r) {
        float h = fmaxf(acc[r] + bv3[ct], 0.f);
        const int row = at * 16 + quad * 4 + r;
        vm[ct] = fmaxf(vm[ct], row < nv ? h : 0.f);
      }
    }
  }
#pragma unroll
  for (int ct = 0; ct < 2; ++ct) {
    vm[ct] = fmaxf(vm[ct], __shfl_xor(vm[ct], 16, 64));
    vm[ct] = fmaxf(vm[ct], __shfl_xor(vm[ct], 32, 64));
  }
  if (quad == 0) {
#pragma unroll
    for (int ct = 0; ct < 2; ++ct) pmax[(2 * wv + ct) * 16 + n] = vm[ct];
  }
  __syncthreads();

  if (tid < 256) out_x[(size_t)cg * 256 + tid] = pmax[tid];
  if (tid < 3) out_pos[cg * 3 + tid] = pos[qb + tid];
  if (tid == 0) out_batch[cg] = (float)b;   // overwrite sel stash
}

extern "C" void kernel_launch(void* const* d_in, const int* in_sizes, int n_in,
                              void* d_out, int out_size, void* d_ws, size_t ws_size,
                              hipStream_t stream) {
  const float* x   = (const float*)d_in[0];
  const float* pos = (const float*)d_in[1];
  // d_in[2] = batch (int32), unused (layout known)
  const float* W1 = (const float*)d_in[3];
  const float* b1 = (const float*)d_in[4];
  const float* W2 = (const float*)d_in[5];
  const float* b2 = (const float*)d_in[6];
  const float* W3 = (const float*)d_in[7];
  const float* b3 = (const float*)d_in[8];

  float* out = (float*)d_out;
  float* out_pos   = out + (size_t)NCENT * 256;
  float* out_batch = out_pos + (size_t)NCENT * 3;   // doubles as sel channel
  f16* ws    = (f16*)d_ws;                          // 122880 B f16 weights
  UI* wsflag = (UI*)((char*)d_ws + 2 * WS_ELEMS);   // publish flag

  // opt-in to >64 KB dynamic LDS (idempotent; host-side, capture-safe)
  hipFuncSetAttribute((const void*)fused_kernel,
                      hipFuncAttributeMaxDynamicSharedMemorySize, DYN_LDS);

  fused_kernel<<<NCLOUD + 1 + NCENT, 512, DYN_LDS, stream>>>(
      x, pos, W1, b1, W2, b2, W3, b3, ws, wsflag,
      out_batch, out, out_pos, out_batch);
}

// Round 11
// 633.939 us; speedup vs baseline: 1.2391x; 1.0106x over previous
//
#include <hip/hip_runtime.h>

typedef unsigned int UI;
typedef unsigned long long ULL;
typedef _Float16 f16;
typedef _Float16 h8 __attribute__((ext_vector_type(8)));
typedef float f32x4 __attribute__((ext_vector_type(4)));
typedef float fl2 __attribute__((ext_vector_type(2)));
typedef UI ui2 __attribute__((ext_vector_type(2)));
typedef double db2 __attribute__((ext_vector_type(2)));

#define NB_PTS 4096
#define MB_SEL 1024
#define KNBR   64
#define NCLOUD 4
#define NCENT  4096

// ws layout (f16): Wt1[128][96] @0 ; Wt2[128][128] @12288 ; Wt3[256][128] @28672
#define WT2_OFF 12288
#define WT3_OFF 28672
#define WS_ELEMS 61440
#define WSFLAG_MAGIC 0x1234ABCDu   // != 0 (memset) and != 0xAAAAAAAA (poison)

// dynamic-LDS layout (bytes). conv view (all < 50 KB):
#define OFF_H1   13312   // h1s [64*136 f16]
#define OFF_H2   30720   // h2s [64*136 f16]
#define OFF_PMAX 48128   // pmax [256 f32]
#define OFF_MASK 49152   // masks [64 ULL]
#define OFF_NBR  49664   // nbrS [64 int]
#define OFF_NV   49920   // nvS int
#define OFF_SHS  49924   // spun sel int
// fps view: pp float4[4096] @0 (64 KB), key slots f64[2][8] @65536
#define OFF_SLOT 65536
// 84 KB > 160/2 KB  =>  exactly ONE block per CU (fps CUs run interference-free)
#define DYN_LDS  86016

// exact np-order squared distance, f64 (radius predicate — proven)
__device__ __forceinline__ double d2_np64(double dx, double dy, double dz) {
  return __dadd_rn(__dadd_rn(__dmul_rn(dx, dx), __dmul_rn(dy, dy)),
                   __dmul_rn(dz, dz));
}

// --- key-as-f64 (r3/r7-proven) ----------------------------------------------
// key = (bits32(dist) << 32) | ~idx. dist in [0,3] fp32 (or the +inf init
// 0x7f800000 as hi word -> f64 exponent field 0x7f8 != all-ones => finite).
// For non-negative finite f64, value ordering == u64 bit ordering, so:
//   v_min_f64(key_acc, cand) with IDENTICAL lo words (same point's ~idx)
//     == np.minimum on the f32 dist, bit-exact.
//   v_max_f64 across points: equal dist => larger ~idx = smaller idx wins
//     == np.argmax first-max, bit-exact.
// Subnormal-range keys (dist~0) can never be the argmax and CDNA f64 min/max
// do not flush denormals. No NaNs possible (finite squares/sums).
// ----------------------------------------------------------------------------

// one f64-max DPP step (bound_ctrl=1 -> OOB lanes read 0 = +0.0, never wins)
template <int CTRL>
__device__ __forceinline__ double dpp_fmax_step(double cur) {
  ULL cu = __builtin_bit_cast(ULL, cur);
  UI lo = (UI)cu, hi = (UI)(cu >> 32);
  UI nl = (UI)__builtin_amdgcn_update_dpp(0, (int)lo, CTRL, 0xf, 0xf, true);
  UI nh = (UI)__builtin_amdgcn_update_dpp(0, (int)hi, CTRL, 0xf, 0xf, true);
  double nv = __builtin_bit_cast(double, ((ULL)nh << 32) | (ULL)nl);
  return fmax(cur, nv);    // v_max_f64
}

// ---------------------------------------------------------------------------
// ONE fused kernel, 512-thr blocks, 1 block/CU (84 KB dynamic LDS).
//
// blocks 0..3: FPS — r9 kernel (verified optimum: 587.5 us dispatch /
//   640.6 us dur, three matched predictions r3/r7/r9). ROUND-10/11: final
//   micro-polish — the post-barrier slot merge reads 4 x ds_read_b128
//   (double2) instead of 8 x ds_read_b64 (kslot is 16B-aligned at both
//   buffer offsets). r10 bench was an INFRA failure (container died twice,
//   no kernel signal; this change is read-only and cannot hang) — resubmit
//   unchanged. Pre-committed: if |delta| < 1% vs r9, the serial-FPS
//   latency floor is confirmed and this is the session's final kernel.
//   Design space exhausted: sync topologies (barrier > ring poll r6 >
//   vmcnt variants r2), wave layouts (4-wave VGPR-dead r1/r4/r5), scan
//   arithmetic (f64 keys r7, matched), LDS-trip fusion (r8, -24%).
//   Floor: 1023 serial iters x {scan issue + DPP reduce + barrier +
//   slot exchange + pp broadcast} ~ 574 ns/iter.
// block 4: weight prep (f32 -> f16 transposed [n][k]) + release flag.
// blocks 5..4100: conv centroid c=idx-5 (r14-proven bitwise path, untouched).
// ---------------------------------------------------------------------------
__global__ __launch_bounds__(512, 2) void fused_kernel(
    const float* __restrict__ x, const float* __restrict__ pos,
    const float* __restrict__ W1, const float* __restrict__ b1,
    const float* __restrict__ W2, const float* __restrict__ b2,
    const float* __restrict__ W3, const float* __restrict__ b3,
    f16* __restrict__ ws, UI* __restrict__ wsflag,
    float* __restrict__ selstash, float* __restrict__ out_x,
    float* __restrict__ out_pos, float* __restrict__ out_batch) {
  extern __shared__ char smem[];
  const int tid  = threadIdx.x;
  const int lane = tid & 63;
  const int wv   = tid >> 6;

  // ======================= role: weight prep (block 4) =====================
  if (blockIdx.x == NCLOUD) {
    for (int t = tid; t < WS_ELEMS; t += 512) {
      if (t < WT2_OFF) {                       // Wt1[n][k] : 128 x 96
        int n = t / 96, k = t - n * 96;
        ws[t] = (k < 67) ? (f16)W1[k * 128 + n] : (f16)0.f;
      } else if (t < WT3_OFF) {                // Wt2[n][k] : 128 x 128
        int u = t - WT2_OFF;
        int n = u >> 7, k = u & 127;
        ws[t] = (f16)W2[k * 128 + n];
      } else {                                 // Wt3[n][k] : 256 x 128
        int u = t - WT3_OFF;
        int n = u >> 7, k = u & 127;
        ws[t] = (f16)W3[k * 256 + n];
      }
    }
    __syncthreads();   // drains all waves' stores before publishing
    if (tid == 0)
      __hip_atomic_store(wsflag, WSFLAG_MAGIC, __ATOMIC_RELEASE,
                         __HIP_MEMORY_SCOPE_AGENT);
    return;
  }

  // ============================ role: FPS (0..3) ===========================
  if (blockIdx.x < NCLOUD) {
#pragma clang fp contract(off)
    asm volatile("s_setprio 3");
    float4* pp    = (float4*)smem;             // 64 KB
    double* kslot = (double*)(smem + OFF_SLOT);// [2][8] f64 keys
    const int b = blockIdx.x;

    fl2 mx[4], my[4], mz[4];
    double key[8];        // per-point f64 key accumulators {~idx, distbits}
    UI nlo[8];            // per-point ~idx (loop-invariant)
#pragma unroll
    for (int t = 0; t < 4; ++t) {
      int j0 = tid + (2 * t) * 512;
      int j1 = tid + (2 * t + 1) * 512;
      size_t a0 = ((size_t)b * NB_PTS + j0) * 3;
      size_t a1 = ((size_t)b * NB_PTS + j1) * 3;
      float X0 = pos[a0], Y0 = pos[a0 + 1], Z0 = pos[a0 + 2];
      float X1 = pos[a1], Y1 = pos[a1 + 1], Z1 = pos[a1 + 2];
      pp[j0] = make_float4(X0, Y0, Z0, 0.f);
      pp[j1] = make_float4(X1, Y1, Z1, 0.f);
      mx[t] = fl2{X0, X1}; my[t] = fl2{Y0, Y1}; mz[t] = fl2{Z0, Z1};
      nlo[2 * t]     = ~(UI)j0;
      nlo[2 * t + 1] = ~(UI)j1;
      ui2 k0; k0.x = nlo[2 * t];     k0.y = 0x7f800000u;   // dist = +inf bits
      ui2 k1; k1.x = nlo[2 * t + 1]; k1.y = 0x7f800000u;
      key[2 * t]     = __builtin_bit_cast(double, k0);
      key[2 * t + 1] = __builtin_bit_cast(double, k1);
    }
    if (tid == 0)
      __hip_atomic_store(&selstash[b * MB_SEL], 1.0f, __ATOMIC_RELAXED,
                         __HIP_MEMORY_SCOPE_AGENT);   // sel 0, encoded +1
    __syncthreads();   // staging fence (once)

    int cur = 0;
    for (int k = 1; k < MB_SEL; ++k) {
      float4 w = pp[cur];               // one b128 broadcast read
#pragma unroll
      for (int t = 0; t < 4; ++t) {
        fl2 dx = mx[t] - w.x;           // v_pk ops; per-comp RN == scalar np
        fl2 dy = my[t] - w.y;
        fl2 dz = mz[t] - w.z;
        fl2 dd = (dx * dx + dy * dy) + dz * dz;   // np order, contract off
        ui2 c0; c0.x = nlo[2 * t];     c0.y = __float_as_uint(dd.x);
        ui2 c1; c1.x = nlo[2 * t + 1]; c1.y = __float_as_uint(dd.y);
        key[2 * t]     = fmin(key[2 * t],
                              __builtin_bit_cast(double, c0));  // v_min_f64
        key[2 * t + 1] = fmin(key[2 * t + 1],
                              __builtin_bit_cast(double, c1));
      }
      // per-lane argmax: depth-3 v_max_f64 tree over the 8 key accumulators
      double a0 = fmax(key[0], key[1]), a1 = fmax(key[2], key[3]);
      double a2 = fmax(key[4], key[5]), a3 = fmax(key[6], key[7]);
      double wk = fmax(fmax(a0, a1), fmax(a2, a3));
      // wave argmax: 6-step DPP f64-max chain -> lane 63 holds wave max
      wk = dpp_fmax_step<0x111>(wk);    // row_shr:1
      wk = dpp_fmax_step<0x112>(wk);    // row_shr:2
      wk = dpp_fmax_step<0x114>(wk);    // row_shr:4
      wk = dpp_fmax_step<0x118>(wk);    // row_shr:8
      wk = dpp_fmax_step<0x142>(wk);    // row_bcast:15
      wk = dpp_fmax_step<0x143>(wk);    // row_bcast:31
      const int buf = (k & 1) * 8;
      if (lane == 63) kslot[buf + wv] = wk;
      // raw barrier: drain only LDS (slot write visible), never vmcnt —
      // the selstash global store stays fire-and-forget (r2-proven).
      asm volatile("s_waitcnt lgkmcnt(0)\n\ts_barrier" ::: "memory");
      // merge reads as 4 x ds_read_b128 (16B-aligned at buf=0 and 64B)
      const db2* sp2 = (const db2*)(kslot + buf);
      db2 p0 = sp2[0], p1 = sp2[1], p2 = sp2[2], p3 = sp2[3];
      double m01 = fmax(p0.x, p0.y);    // tree merge, v_max_f64 each
      double m23 = fmax(p1.x, p1.y);
      double m45 = fmax(p2.x, p2.y);
      double m67 = fmax(p3.x, p3.y);
      double mk  = fmax(fmax(m01, m23), fmax(m45, m67));
      int winner = (int)(~(UI)__builtin_bit_cast(ULL, mk));
      cur = winner;
      // fire-and-forget publication after the dependent chain is unblocked
      if (tid == 0)
        __hip_atomic_store(&selstash[b * MB_SEL + k], (float)(winner + 1),
                           __ATOMIC_RELAXED, __HIP_MEMORY_SCOPE_AGENT);
    }
    return;
  }

  // ============================ role: conv =================================
  f16* featA  = (f16*)smem;
  f16* h1s    = (f16*)(smem + OFF_H1);
  f16* h2s    = (f16*)(smem + OFF_H2);
  float* pmax = (float*)(smem + OFF_PMAX);
  ULL* masks  = (ULL*)(smem + OFF_MASK);
  int* nbrS   = (int*)(smem + OFF_NBR);
  int* nvP    = (int*)(smem + OFF_NV);
  int* shS    = (int*)(smem + OFF_SHS);

  const int c  = (int)blockIdx.x - (NCLOUD + 1);
  const int k  = c >> 2;
  const int b  = c & 3;
  const int cg = b * MB_SEL + k;     // global centroid id (output index)

  // gate 1: weights ready (release/acquire covers the non-atomic ws payload)
  if (tid == 0) {
    while (__hip_atomic_load(wsflag, __ATOMIC_ACQUIRE,
                             __HIP_MEMORY_SCOPE_AGENT) != WSFLAG_MAGIC)
      __builtin_amdgcn_s_sleep(2);
  }
  __syncthreads();

  // B1/B2 + bias preload (8 waves own 16 cols each for L1/L2, 32 for L3)
  const int n    = lane & 15;
  const int quad = lane >> 4;
  const int col  = wv * 16 + n;       // L1/L2 column
  h8 B1f[3], B2f[4];
  float bv1, bv2, bv3[2];
  bv1 = b1[col];
  bv2 = b2[col];
#pragma unroll
  for (int kt = 0; kt < 3; ++kt)
    B1f[kt] = *(const h8*)(ws + col * 96 + kt * 32 + quad * 8);
#pragma unroll
  for (int kt = 0; kt < 4; ++kt)
    B2f[kt] = *(const h8*)(ws + WT2_OFF + col * 128 + kt * 32 + quad * 8);
#pragma unroll
  for (int ct = 0; ct < 2; ++ct) bv3[ct] = b3[(2 * wv + ct) * 16 + n];

  // gate 2: own sel ready (value IS the payload; winner+1 >= 1;
  // both init states — memset-0 and 0xAA poison — read as "not ready")
  if (tid == 0) {
    float v;
    for (;;) {
      v = __hip_atomic_load(&selstash[cg], __ATOMIC_RELAXED,
                            __HIP_MEMORY_SCOPE_AGENT);
      if (v >= 1.0f) break;
      __builtin_amdgcn_s_sleep(8);
    }
    *shS = (int)v - 1;
  }
  __syncthreads();
  const int s = (*shS) & (NB_PTS - 1);

  const size_t qb = ((size_t)(b * NB_PTS + s)) * 3;
  const float qxf = pos[qb], qyf = pos[qb + 1], qzf = pos[qb + 2];
  const double qx = (double)qxf, qy = (double)qyf, qz = (double)qzf;
  const double RR = 0.2 * 0.2;

  // radius: in-ball bitmask over all 4096 points (f64, np-exact).
  // 8 waves x 8 chunks = 64 chunks of 64 points.
#pragma unroll
  for (int it = 0; it < 8; ++it) {
    const int ch = wv * 8 + it;
    const int j  = ch * 64 + lane;
    const size_t pb = ((size_t)b * NB_PTS + j) * 3;
    double d2 = d2_np64((double)pos[pb] - qx, (double)pos[pb + 1] - qy,
                        (double)pos[pb + 2] - qz);
    ULL m = __ballot(d2 <= RR);
    if (lane == 0) masks[ch] = m;
  }
  __syncthreads();

  // wave 0: first-64 in-ball extraction (ascending index)
  if (tid < 64) {
    ULL m = masks[tid];
    int pc = __popcll(m);
    int incl = pc;
#pragma unroll
    for (int off = 1; off < 64; off <<= 1) {
      int o = __shfl_up(incl, off, 64);
      if (tid >= off) incl += o;
    }
    int base = incl - pc;
    int tot  = __shfl(incl, 63, 64);
    int nvw  = min(tot, KNBR);
    if (tid == 63) *nvP = nvw;
    int slot = base;
    ULL mm = m;
    while (mm && slot < KNBR) {
      int bit = __ffsll(mm) - 1;
      nbrS[slot++] = tid * 64 + bit;
      mm &= mm - 1;
    }
    if (tid >= nvw) nbrS[tid] = s;
  }
  __syncthreads();
  const int nv = *nvP;

  // gather: feat=[x_j, pos_j-pos_i, 0-pad] as f16, rows 0..63 (8 thr/row)
  {
    const int r = tid >> 3;
    const int part = tid & 7;
    const int g = nbrS[r];
    const float* xrow = x + (((size_t)(b * NB_PTS + g)) << 6) + part * 8;
    float4 u0 = *(const float4*)(xrow);
    float4 u1 = *(const float4*)(xrow + 4);
    h8 o0;
    o0[0]=(f16)u0.x; o0[1]=(f16)u0.y; o0[2]=(f16)u0.z; o0[3]=(f16)u0.w;
    o0[4]=(f16)u1.x; o0[5]=(f16)u1.y; o0[6]=(f16)u1.z; o0[7]=(f16)u1.w;
    *(h8*)(featA + r * 104 + part * 8) = o0;
    if (part == 7) {
      size_t gb = ((size_t)(b * NB_PTS + g)) * 3;
      h8 rv = {(f16)0.f,(f16)0.f,(f16)0.f,(f16)0.f,(f16)0.f,(f16)0.f,(f16)0.f,(f16)0.f};
      rv[0] = (f16)(pos[gb]     - qxf);
      rv[1] = (f16)(pos[gb + 1] - qyf);
      rv[2] = (f16)(pos[gb + 2] - qzf);
      h8 z = {(f16)0.f,(f16)0.f,(f16)0.f,(f16)0.f,(f16)0.f,(f16)0.f,(f16)0.f,(f16)0.f};
      *(h8*)(featA + r * 104 + 64) = rv;
      *(h8*)(featA + r * 104 + 72) = z;
      *(h8*)(featA + r * 104 + 80) = z;
      *(h8*)(featA + r * 104 + 88) = z;
    }
  }
  __syncthreads();

  // L1: 67(->96) -> 128 ; wave w owns cols [16w,16w+16)
#pragma unroll
  for (int at = 0; at < 4; ++at) {
    f32x4 acc = {0.f, 0.f, 0.f, 0.f};
#pragma unroll
    for (int kt = 0; kt < 3; ++kt) {
      h8 a = *(const h8*)(featA + (at * 16 + n) * 104 + kt * 32 + quad * 8);
      acc = __builtin_amdgcn_mfma_f32_16x16x32_f16(a, B1f[kt], acc, 0, 0, 0);
    }
#pragma unroll
    for (int r = 0; r < 4; ++r)
      h1s[(at * 16 + quad * 4 + r) * 136 + col] = (f16)fmaxf(acc[r] + bv1, 0.f);
  }
  __syncthreads();

  // L2: 128 -> 128
#pragma unroll
  for (int at = 0; at < 4; ++at) {
    f32x4 acc = {0.f, 0.f, 0.f, 0.f};
#pragma unroll
    for (int kt = 0; kt < 4; ++kt) {
      h8 a = *(const h8*)(h1s + (at * 16 + n) * 136 + kt * 32 + quad * 8);
      acc = __builtin_amdgcn_mfma_f32_16x16x32_f16(a, B2f[kt], acc, 0, 0, 0);
    }
#pragma unroll
    for (int r = 0; r < 4; ++r)
      h2s[(at * 16 + quad * 4 + r) * 136 + col] = (f16)fmaxf(acc[r] + bv2, 0.f);
  }
  __syncthreads();

  // L3: 128 -> 256, wave w owns cols [32w,32w+32); B3 streamed from L2
  float vm[2] = {0.f, 0.f};   // valid max >= 0 (relu, nv>=1)
#pragma unroll
  for (int at = 0; at < 4; ++at) {
#pragma unroll
    for (int ct = 0; ct < 2; ++ct) {
      const int c3 = (2 * wv + ct) * 16 + n;
      f32x4 acc = {0.f, 0.f, 0.f, 0.f};
#pragma unroll
      for (int kt = 0; kt < 4; ++kt) {
        h8 a = *(const h8*)(h2s + (at * 16 + n) * 136 + kt * 32 + quad * 8);
        h8 wfr = *(const h8*)(ws + WT3_OFF + c3 * 128 + kt * 32 + quad * 8);
        acc = __builtin_amdgcn_mfma_f32_16x16x32_f16(a, wfr, acc, 0, 0, 0);
      }
#pragma unroll
      for (int r = 0; r < 4; ++r) {
        float h = fmaxf(acc[r] + bv3[ct], 0.f);
        const int row = at * 16 + quad * 4 + r;
        vm[ct] = fmaxf(vm[ct], row < nv ? h : 0.f);
      }
    }
  }
#pragma unroll
  for (int ct = 0; ct < 2; ++ct) {
    vm[ct] = fmaxf(vm[ct], __shfl_xor(vm[ct], 16, 64));
    vm[ct] = fmaxf(vm[ct], __shfl_xor(vm[ct], 32, 64));
  }
  if (quad == 0) {
#pragma unroll
    for (int ct = 0; ct < 2; ++ct) pmax[(2 * wv + ct) * 16 + n] = vm[ct];
  }
  __syncthreads();

  if (tid < 256) out_x[(size_t)cg * 256 + tid] = pmax[tid];
  if (tid < 3) out_pos[cg * 3 + tid] = pos[qb + tid];
  if (tid == 0) out_batch[cg] = (float)b;   // overwrite sel stash
}

extern "C" void kernel_launch(void* const* d_in, const int* in_sizes, int n_in,
                              void* d_out, int out_size, void* d_ws, size_t ws_size,
                              hipStream_t stream) {
  const float* x   = (const float*)d_in[0];
  const float* pos = (const float*)d_in[1];
  // d_in[2] = batch (int32), unused (layout known)
  const float* W1 = (const float*)d_in[3];
  const float* b1 = (const float*)d_in[4];
  const float* W2 = (const float*)d_in[5];
  const float* b2 = (const float*)d_in[6];
  const float* W3 = (const float*)d_in[7];
  const float* b3 = (const float*)d_in[8];

  float* out = (float*)d_out;
  float* out_pos   = out + (size_t)NCENT * 256;
  float* out_batch = out_pos + (size_t)NCENT * 3;   // doubles as sel channel
  f16* ws    = (f16*)d_ws;                          // 122880 B f16 weights
  UI* wsflag = (UI*)((char*)d_ws + 2 * WS_ELEMS);   // publish flag

  // opt-in to >64 KB dynamic LDS (idempotent; host-side, capture-safe)
  hipFuncSetAttribute((const void*)fused_kernel,
                      hipFuncAttributeMaxDynamicSharedMemorySize, DYN_LDS);

  fused_kernel<<<NCLOUD + 1 + NCENT, 512, DYN_LDS, stream>>>(
      x, pos, W1, b1, W2, b2, W3, b3, ws, wsflag,
      out_batch, out, out_pos, out_batch);
}